// Round 4
// baseline (554.969 us; speedup 1.0000x reference)
//
#include <hip/hip_runtime.h>

// SNN classifier: h_all = x @ W1^T + b1 via f16 split-2 MFMA (3 GEMM terms,
// fp32-grade accuracy), then sequential LIF scan over T=25.
//   x  [B=128, T=25, F=12288] f32 ; W1 [2048, 12288] ; Wo [2,2048]
// Split: x = Ah+Al (f16), W*128 = Bh+Bl (f16); h*128 = AhBh + AhBl + AlBh.
//
// GEMM: 256x256 block tile, 512 thr (8 waves 2Mx4N), wave-tile 128x64
// (0.25 ds_reads per MFMA, 1 barrier per 96 MFMAs/wave). K-split 2 for
// occupancy: grid 13*8*2 = 208 blocks; two partial fp32 buffers, reduced
// deterministically inside the LIF kernel (h = (p0+p1)*2^-7 + b1).
// LDS 128KB = 2 x (A 32K | B 32K) double buffer; stage(kt+1) issued after
// the per-tile __syncthreads (race-free; per-tile compute ~3.7k cyc hides
// HBM latency so the vmcnt(0) inside syncthreads never stalls).
// LDS image [k-slot 0..7][row][16B] (hi slots 0-3, lo 4-7): ds_read_b128 is
// 16-lane contiguous -> conflict-free; conversion kernels pre-write this
// exact image so global_load_lds stays linear (guide rule #21).

#define T_STEPS 25
#define B_SZ    128
#define F_SZ    12288
#define HID_SZ  2048
#define KT      384            // F / 32
#define KT2     192            // K-tiles per split block
#define A_CH    32768          // 256 rows * 32 k * 4B (f16 hi+lo)
#define B_CH    32768          // 256 cols * 32 k * 4B
#define M_PAD   3328           // 13 * 256

typedef __attribute__((ext_vector_type(8))) _Float16 f16x8;
typedef __attribute__((ext_vector_type(4))) float f32x4;

__device__ __forceinline__ void g2l16(const void* g, void* l) {
  __builtin_amdgcn_global_load_lds(
      (const __attribute__((address_space(1))) void*)g,
      (__attribute__((address_space(3))) void*)l, 16, 0, 0);
}

// ---- conversion: x -> A2 [mt][ks][slot][r 0..255][16B] ---------------------
__global__ __launch_bounds__(256) void conv_x_kernel(
    const float* __restrict__ x, char* __restrict__ A2) {
  const int total = 13 * KT * 256 * 4;  // (mt,ks,r,s)
  for (int i = blockIdx.x * 256 + threadIdx.x; i < total; i += gridDim.x * 256) {
    const int s = i & 3;
    const int r = (i >> 2) & 255;
    const int rest = i >> 10;            // mt*KT + ks
    const int ks = rest % KT;
    const int mt = rest / KT;
    const int m = mt * 256 + r;          // padded row
    const int b = m & 127;
    const int t = m >> 7;
    f16x8 hi = {0, 0, 0, 0, 0, 0, 0, 0};
    f16x8 lo = {0, 0, 0, 0, 0, 0, 0, 0};
    if (t < T_STEPS) {
      const float* src = x + ((size_t)(b * T_STEPS + t)) * F_SZ + ks * 32 + s * 8;
      float4 v0 = *(const float4*)src;
      float4 v1 = *(const float4*)(src + 4);
      float vf[8] = {v0.x, v0.y, v0.z, v0.w, v1.x, v1.y, v1.z, v1.w};
#pragma unroll
      for (int j = 0; j < 8; ++j) {
        _Float16 h = (_Float16)vf[j];
        hi[j] = h;
        lo[j] = (_Float16)(vf[j] - (float)h);
      }
    }
    char* chunk = A2 + (size_t)rest * A_CH;
    *(f16x8*)(chunk + s * 4096 + r * 16) = hi;          // slots 0-3: hi
    *(f16x8*)(chunk + (s + 4) * 4096 + r * 16) = lo;    // slots 4-7: lo
  }
}

// ---- conversion: W1*128 -> B2 [nt 0..7][ks][slot][r 0..255][16B] -----------
__global__ __launch_bounds__(256) void conv_w_kernel(
    const float* __restrict__ W1, char* __restrict__ B2) {
  const int total = 8 * KT * 256 * 4;
  for (int i = blockIdx.x * 256 + threadIdx.x; i < total; i += gridDim.x * 256) {
    const int s = i & 3;
    const int r = (i >> 2) & 255;
    const int rest = i >> 10;            // nt*KT + ks
    const int ks = rest % KT;
    const int nt = rest / KT;
    const float* src = W1 + ((size_t)(nt * 256 + r)) * F_SZ + ks * 32 + s * 8;
    float4 v0 = *(const float4*)src;
    float4 v1 = *(const float4*)(src + 4);
    float vf[8] = {v0.x, v0.y, v0.z, v0.w, v1.x, v1.y, v1.z, v1.w};
    f16x8 hi, lo;
#pragma unroll
    for (int j = 0; j < 8; ++j) {
      float vs = vf[j] * 128.0f;         // scale keeps residual f16-normal
      _Float16 h = (_Float16)vs;
      hi[j] = h;
      lo[j] = (_Float16)(vs - (float)h);
    }
    char* chunk = B2 + (size_t)rest * B_CH;
    *(f16x8*)(chunk + s * 4096 + r * 16) = hi;
    *(f16x8*)(chunk + (s + 4) * 4096 + r * 16) = lo;
  }
}

// ---- MFMA GEMM: 256x256 tile, wave-tile 128x64, K-split 2 ------------------
__global__ __launch_bounds__(512, 2) void gemm_mfma_kernel(
    const char* __restrict__ A2, const char* __restrict__ B2,
    float* __restrict__ parts) {
  // LDS: buf b at b*65536: [A 32K | B 32K]
  __shared__ __align__(16) char lds[131072];
  const int tid = threadIdx.x;
  const int l = tid & 63;
  const int w = tid >> 6;      // wave 0..7
  const int wm = w >> 2;       // 0..1 : rows wm*128..+128
  const int wn = w & 3;        // 0..3 : cols wn*64..+64

  // XCD-aware bijective swizzle (208 = 8 XCDs * 26)
  const int bid = blockIdx.x;
  const int swz = (bid & 7) * 26 + (bid >> 3);
  const int mt = swz >> 4;       // 0..12
  const int nt = (swz >> 1) & 7; // 0..7
  const int sp = swz & 1;        // K-split half
  const char* aSrc = A2 + (size_t)(mt * KT + sp * KT2) * A_CH;
  const char* bSrc = B2 + (size_t)(nt * KT + sp * KT2) * B_CH;

#define STAGE(ktx)                                                         \
  do {                                                                     \
    const char* sa_ = aSrc + (size_t)(ktx) * A_CH + tid * 16;              \
    const char* sb_ = bSrc + (size_t)(ktx) * B_CH + tid * 16;              \
    char* da_ = (char*)lds + ((ktx) & 1) * 65536 + w * 1024;               \
    char* db_ = da_ + 32768;                                               \
    g2l16(sa_, da_);                 g2l16(sa_ + 8192, da_ + 8192);        \
    g2l16(sa_ + 16384, da_ + 16384); g2l16(sa_ + 24576, da_ + 24576);     \
    g2l16(sb_, db_);                 g2l16(sb_ + 8192, db_ + 8192);        \
    g2l16(sb_ + 16384, db_ + 16384); g2l16(sb_ + 24576, db_ + 24576);     \
  } while (0)

  f32x4 acc[8][4];
#pragma unroll
  for (int i = 0; i < 8; ++i)
#pragma unroll
    for (int j = 0; j < 4; ++j) acc[i][j] = (f32x4){0.f, 0.f, 0.f, 0.f};

  // fragment LDS offsets: slot = l>>4 (k = slot*8..+8), row = base + (l&15)
  const int aoff = (l >> 4) * 4096 + (wm * 128 + (l & 15)) * 16;
  const int boff = (l >> 4) * 4096 + (wn * 64 + (l & 15)) * 16;

#define MM3(mf, nf, AH, AL, BH, BL)                                                      \
  acc[mf][nf] = __builtin_amdgcn_mfma_f32_16x16x32_f16(AH, BH, acc[mf][nf], 0, 0, 0);    \
  acc[mf][nf] = __builtin_amdgcn_mfma_f32_16x16x32_f16(AH, BL, acc[mf][nf], 0, 0, 0);    \
  acc[mf][nf] = __builtin_amdgcn_mfma_f32_16x16x32_f16(AL, BH, acc[mf][nf], 0, 0, 0);

  STAGE(0);  // prologue

  for (int kt = 0; kt < KT2; ++kt) {
    __syncthreads();               // drains stage(kt) (issued a full tile ago)
    if (kt + 1 < KT2) STAGE(kt + 1);

    const char* la = (const char*)lds + (kt & 1) * 65536;
    const char* lb = la + 32768;

    f16x8 ah[8], al[8];
#pragma unroll
    for (int mf = 0; mf < 8; ++mf) {
      ah[mf] = *(const f16x8*)(la + aoff + mf * 256);
      al[mf] = *(const f16x8*)(la + aoff + 16384 + mf * 256);
    }
#pragma unroll
    for (int nf = 0; nf < 4; ++nf) {
      f16x8 bh = *(const f16x8*)(lb + boff + nf * 256);
      f16x8 bl = *(const f16x8*)(lb + boff + 16384 + nf * 256);
      __builtin_amdgcn_s_setprio(1);
      MM3(0, nf, ah[0], al[0], bh, bl)
      MM3(1, nf, ah[1], al[1], bh, bl)
      MM3(2, nf, ah[2], al[2], bh, bl)
      MM3(3, nf, ah[3], al[3], bh, bl)
      MM3(4, nf, ah[4], al[4], bh, bl)
      MM3(5, nf, ah[5], al[5], bh, bl)
      MM3(6, nf, ah[6], al[6], bh, bl)
      MM3(7, nf, ah[7], al[7], bh, bl)
      __builtin_amdgcn_s_setprio(0);
    }
  }

  // epilogue: write raw partial acc.  C/D frag: col=lane&15, row=(lane>>4)*4+q
  float* dst = parts + (size_t)sp * ((size_t)M_PAD * HID_SZ);
  const int row0 = mt * 256 + wm * 128 + (l >> 4) * 4;
  const int col0 = nt * 256 + wn * 64 + (l & 15);
#pragma unroll
  for (int nf = 0; nf < 4; ++nf) {
    const int col = col0 + nf * 16;
#pragma unroll
    for (int mf = 0; mf < 8; ++mf) {
#pragma unroll
      for (int q = 0; q < 4; ++q) {
        const int row = row0 + mf * 16 + q;
        dst[(size_t)row * HID_SZ + col] = acc[mf][nf][q];
      }
    }
  }
#undef STAGE
#undef MM3
}

// ---- fallback fp32 vector GEMM (used only if ws too small) -----------------
__global__ __launch_bounds__(256) void gemm_h_kernel(
    const float* __restrict__ x, const float* __restrict__ W1,
    const float* __restrict__ b1, float* __restrict__ h_all) {
  __shared__ float As[16][128];
  __shared__ float Bs[16][128];
  const int tid = threadIdx.x;
  const int tx = tid & 15;
  const int ty = tid >> 4;
  const int m0 = blockIdx.x * 128;
  const int n0 = blockIdx.y * 128;
  const int lrow = tid >> 1;
  const int lcol = (tid & 1) * 8;
  const int gm = m0 + lrow;
  const int bb = gm & (B_SZ - 1);
  const int tt = gm >> 7;
  const float* aptr = x + ((size_t)bb * T_STEPS + tt) * F_SZ + lcol;
  const float* bptr = W1 + (size_t)(n0 + lrow) * F_SZ + lcol;
  float acc[8][8];
#pragma unroll
  for (int i = 0; i < 8; ++i)
#pragma unroll
    for (int j = 0; j < 8; ++j) acc[i][j] = 0.f;
  for (int k0 = 0; k0 < F_SZ; k0 += 16) {
    float4 av0 = *(const float4*)(aptr + k0);
    float4 av1 = *(const float4*)(aptr + k0 + 4);
    float4 bv0 = *(const float4*)(bptr + k0);
    float4 bv1 = *(const float4*)(bptr + k0 + 4);
    As[lcol + 0][lrow] = av0.x; As[lcol + 1][lrow] = av0.y;
    As[lcol + 2][lrow] = av0.z; As[lcol + 3][lrow] = av0.w;
    As[lcol + 4][lrow] = av1.x; As[lcol + 5][lrow] = av1.y;
    As[lcol + 6][lrow] = av1.z; As[lcol + 7][lrow] = av1.w;
    Bs[lcol + 0][lrow] = bv0.x; Bs[lcol + 1][lrow] = bv0.y;
    Bs[lcol + 2][lrow] = bv0.z; Bs[lcol + 3][lrow] = bv0.w;
    Bs[lcol + 4][lrow] = bv1.x; Bs[lcol + 5][lrow] = bv1.y;
    Bs[lcol + 6][lrow] = bv1.z; Bs[lcol + 7][lrow] = bv1.w;
    __syncthreads();
#pragma unroll
    for (int k = 0; k < 16; ++k) {
      float4 a0 = *(const float4*)&As[k][ty * 8];
      float4 a1 = *(const float4*)&As[k][ty * 8 + 4];
      float4 q0 = *(const float4*)&Bs[k][tx * 8];
      float4 q1 = *(const float4*)&Bs[k][tx * 8 + 4];
      float ar[8] = {a0.x, a0.y, a0.z, a0.w, a1.x, a1.y, a1.z, a1.w};
      float br[8] = {q0.x, q0.y, q0.z, q0.w, q1.x, q1.y, q1.z, q1.w};
#pragma unroll
      for (int i = 0; i < 8; ++i)
#pragma unroll
        for (int j = 0; j < 8; ++j)
          acc[i][j] = fmaf(ar[i], br[j], acc[i][j]);
    }
    __syncthreads();
  }
#pragma unroll
  for (int i = 0; i < 8; ++i) {
    const int gm2 = m0 + ty * 8 + i;
    float* orow = h_all + (size_t)gm2 * HID_SZ + n0 + tx * 8;
    const float* brow = b1 + n0 + tx * 8;
#pragma unroll
    for (int j = 0; j < 8; ++j) orow[j] = acc[i][j] + brow[j];
  }
}

// ---- LIF scan over T (fused partial-sum reduce) ----------------------------
__global__ __launch_bounds__(256) void lif_scan_kernel(
    const float* __restrict__ p0, const float* __restrict__ p1,
    const float* __restrict__ b1, const float* __restrict__ Wo,
    const float* __restrict__ bo, float* __restrict__ out, int two_parts) {
  const int b = blockIdx.x;
  const int tid = threadIdx.x;
  float mem1[8];
  float wo0[8], wo1[8], bv[8];
#pragma unroll
  for (int i = 0; i < 8; ++i) {
    mem1[i] = 0.f;
    wo0[i] = Wo[tid + 256 * i];
    wo1[i] = Wo[HID_SZ + tid + 256 * i];
    bv[i] = b1[tid + 256 * i];
  }
  __shared__ float partial[4][2];
  float memo0 = 0.f, memo1 = 0.f, acc0 = 0.f, acc1 = 0.f;
  const float bo0 = bo[0], bo1 = bo[1];
  for (int t = 0; t < T_STEPS; ++t) {
    const size_t rowb = ((size_t)t * B_SZ + b) * HID_SZ;
    float p0v = 0.f, p1v = 0.f;
    float pr0 = 0.f, pr1 = 0.f;
#pragma unroll
    for (int i = 0; i < 8; ++i) {
      const size_t idx = rowb + tid + 256 * i;
      float h;
      if (two_parts)
        h = (p0[idx] + p1[idx]) * 0.0078125f + bv[i];
      else
        h = p0[idx];  // fallback path: already biased
      float r1 = mem1[i] > 1.0f ? 1.0f : 0.0f;
      float m = 0.9f * mem1[i] + h - r1;
      mem1[i] = m;
      if (m > 1.0f) { pr0 += wo0[i]; pr1 += wo1[i]; }
    }
#pragma unroll
    for (int off = 32; off > 0; off >>= 1) {
      pr0 += __shfl_down(pr0, off);
      pr1 += __shfl_down(pr1, off);
    }
    const int wave = tid >> 6;
    if ((tid & 63) == 0) { partial[wave][0] = pr0; partial[wave][1] = pr1; }
    __syncthreads();
    if (tid == 0) {
      float o0 = partial[0][0] + partial[1][0] + partial[2][0] + partial[3][0] + bo0;
      float o1 = partial[0][1] + partial[1][1] + partial[2][1] + partial[3][1] + bo1;
      float ro0 = memo0 > 1.0f ? 1.0f : 0.0f;
      float ro1 = memo1 > 1.0f ? 1.0f : 0.0f;
      memo0 = 0.9f * memo0 + o0 - ro0;
      memo1 = 0.9f * memo1 + o1 - ro1;
      acc0 += memo0 > 1.0f ? 1.0f : 0.0f;
      acc1 += memo1 > 1.0f ? 1.0f : 0.0f;
    }
    __syncthreads();
    (void)p0v; (void)p1v;
  }
  if (tid == 0) {
    out[b * 2 + 0] = acc0;
    out[b * 2 + 1] = acc1;
  }
}

extern "C" void kernel_launch(void* const* d_in, const int* in_sizes, int n_in,
                              void* d_out, int out_size, void* d_ws, size_t ws_size,
                              hipStream_t stream) {
  const float* x  = (const float*)d_in[0];
  const float* W1 = (const float*)d_in[1];
  const float* b1 = (const float*)d_in[2];
  const float* Wo = (const float*)d_in[3];
  const float* bo = (const float*)d_in[4];
  float* out = (float*)d_out;

  const size_t part_bytes = (size_t)M_PAD * HID_SZ * 4;        // 27.26 MB
  const size_t a2_bytes = (size_t)13 * KT * A_CH;              // 163.6 MB
  const size_t b2_bytes = (size_t)8 * KT * B_CH;               // 100.7 MB
  char* ws = (char*)d_ws;
  float* parts = (float*)ws;                                   // p0 | p1

  if (ws_size >= 2 * part_bytes + a2_bytes + b2_bytes) {
    char* A2 = ws + 2 * part_bytes;
    char* B2 = A2 + a2_bytes;
    conv_x_kernel<<<2048, 256, 0, stream>>>(x, A2);
    conv_w_kernel<<<2048, 256, 0, stream>>>(W1, B2);
    gemm_mfma_kernel<<<208, 512, 0, stream>>>(A2, B2, parts);
    lif_scan_kernel<<<B_SZ, 256, 0, stream>>>(
        parts, parts + (size_t)M_PAD * HID_SZ, b1, Wo, bo, out, 1);
  } else {
    dim3 grid(25, 16);
    gemm_h_kernel<<<grid, 256, 0, stream>>>(x, W1, b1, (float*)ws);
    lif_scan_kernel<<<B_SZ, 256, 0, stream>>>(
        (const float*)ws, (const float*)ws, b1, Wo, bo, out, 0);
  }
}